// Round 2
// 295.963 us; speedup vs baseline: 1.1107x; 1.1107x over previous
//
#include <hip/hip_runtime.h>
#include <math.h>
#include <limits.h>

#define TPB   256
#define TILE  1024          // items per block-tile (256 thr x 4 rounds)
#define RNDS  4
#define MAXT  2048
#define TPAD  64            // pad so unconditional reads past e stay in-bounds
#define MAXK  1024
#define MAXW  29            // max span width in this problem (W=30 -> w<=29)
#define BATCH 512           // greedy candidates per round (2 per thread)

// ===========================================================================
// Kernel A: fused key-build + 4-pass LSD radix argsort (60 blocks, grid bars)
// ===========================================================================
struct SortSM {
  union {
    unsigned h[4 * 256];                  // P0: 4 pass histograms
    struct {
      unsigned wcnt[4][256];              // [wave][digit] (also scan scratch)
      unsigned runCnt[256];
      unsigned baseL[256];
    } pass;
  };
};

// Device-scope grid barrier. SAFE: grid (<=60 blocks) fully co-resident on
// 256 CUs. ctr[] zeroed by memset node each launch.
__device__ inline void gbar(unsigned* ctr, int idx, unsigned nblk) {
  __syncthreads();
  if (threadIdx.x == 0) {
    __threadfence();
    atomicAdd(&ctr[idx], 1u);
    while (atomicAdd(&ctr[idx], 0u) < nblk) { __builtin_amdgcn_s_sleep(8); }
    __threadfence();
  }
  __syncthreads();
}

__global__ void __launch_bounds__(TPB, 1) sort_kernel(
    const float* __restrict__ scores, const float* __restrict__ mask,
    int N, int nT, unsigned* ctr, unsigned* ghist, unsigned* tileCnt,
    unsigned* keysA, unsigned* keysB, int* idxA, int* idxB) {
  __shared__ SortSM s;
  const int tid = threadIdx.x;
  const int lane = tid & 63;
  const int wave = tid >> 6;

  // ---- P0: build keys + all 4 histograms in one read ----
  for (int j = tid; j < 1024; j += TPB) s.h[j] = 0;
  __syncthreads();
  {
    const int tile0 = blockIdx.x * TILE;
    for (int r = 0; r < RNDS; ++r) {
      int i = tile0 + r * 256 + tid;
      if (i < N) {
        float kf = scores[i] + logf(mask[i]);          // mask==1 -> +0 exact
        unsigned u = __float_as_uint(kf);
        u = (u & 0x80000000u) ? ~u : (u | 0x80000000u);
        u = ~u;                                        // descending order
        keysA[i] = u;
        atomicAdd(&s.h[(u & 255u)], 1u);
        atomicAdd(&s.h[256 + ((u >> 8) & 255u)], 1u);
        atomicAdd(&s.h[512 + ((u >> 16) & 255u)], 1u);
        atomicAdd(&s.h[768 + (u >> 24)], 1u);
      }
    }
    __syncthreads();
    for (int j = tid; j < 1024; j += TPB)
      if (s.h[j]) atomicAdd(&ghist[j], s.h[j]);
  }
  gbar(ctr, 0, nT);

  // ---- P1: block 0 scans digit bases (4x256 exclusive) ----
  if (blockIdx.x == 0) {
    for (int p = 0; p < 4; ++p) {
      unsigned v = ghist[p * 256 + tid];
      unsigned* A = s.pass.wcnt[0];
      unsigned* B = s.pass.wcnt[1];
      A[tid] = v;
      __syncthreads();
      for (int off = 1; off < 256; off <<= 1) {
        B[tid] = A[tid] + ((tid >= off) ? A[tid - off] : 0u);
        __syncthreads();
        unsigned* t = A; A = B; B = t;
      }
      ghist[p * 256 + tid] = A[tid] - v;
      __syncthreads();
    }
  }
  gbar(ctr, 1, nT);

  // ---- 4 fused rank/scatter radix passes ----
  for (int p = 0; p < 4; ++p) {
    const unsigned* srck = (p & 1) ? keysB : keysA;
    const int*      srci = (p & 1) ? idxB : idxA;     // p==0: payload = i
    unsigned*       dstk = (p & 1) ? keysA : keysB;
    int*            dsti = (p & 1) ? idxA : idxB;
    const int shift = 8 * p;
    const int tile0 = blockIdx.x * TILE;

    s.pass.runCnt[tid] = 0;
    unsigned mykey[RNDS]; int mypay[RNDS]; unsigned mypos[RNDS]; bool myval[RNDS];
    #pragma unroll
    for (int r = 0; r < RNDS; ++r) {
      __syncthreads();
      s.pass.wcnt[0][tid] = 0; s.pass.wcnt[1][tid] = 0;
      s.pass.wcnt[2][tid] = 0; s.pass.wcnt[3][tid] = 0;
      __syncthreads();
      int i = tile0 + r * 256 + tid;
      bool v = (i < N);
      unsigned key = v ? srck[i] : 0u;
      int pay = v ? ((p == 0) ? i : srci[i]) : 0;
      unsigned d = (key >> shift) & 255u;
      unsigned long long mm = __ballot(v);     // stable rank within wave
      #pragma unroll
      for (int b = 0; b < 8; ++b) {
        unsigned long long bb = __ballot((d >> b) & 1u);
        mm &= ((d >> b) & 1u) ? bb : ~bb;
      }
      int rank = (int)__popcll(mm & ((1ull << lane) - 1ull));
      if (v && rank == 0) s.pass.wcnt[wave][d] = (unsigned)__popcll(mm);
      __syncthreads();
      unsigned run0 = s.pass.runCnt[tid];
      unsigned run = 0;
      #pragma unroll
      for (int w2 = 0; w2 < 4; ++w2) {
        unsigned c = s.pass.wcnt[w2][tid];
        s.pass.wcnt[w2][tid] = run0 + run;
        run += c;
      }
      s.pass.runCnt[tid] = run0 + run;
      __syncthreads();
      mykey[r] = key; mypay[r] = pay; myval[r] = v;
      mypos[r] = v ? (s.pass.wcnt[wave][d] + (unsigned)rank) : 0u;
    }
    __syncthreads();
    tileCnt[blockIdx.x * 256 + tid] = s.pass.runCnt[tid];
    gbar(ctr, 2 + 2 * p, nT);

    unsigned baseacc = ghist[p * 256 + tid];
    for (int t = 0; t < blockIdx.x; ++t)
      baseacc += tileCnt[t * 256 + tid];
    s.pass.baseL[tid] = baseacc;
    __syncthreads();
    #pragma unroll
    for (int r = 0; r < RNDS; ++r) {
      if (myval[r]) {
        unsigned d = (mykey[r] >> shift) & 255u;
        unsigned pos = s.pass.baseL[d] + mypos[r];
        dstk[pos] = mykey[r];
        dsti[pos] = mypay[r];
      }
    }
    if (p < 3) gbar(ctr, 3 + 2 * p, nT);
  }
  // final order in idxA (A->B->A->B->A)
}

// ===========================================================================
// Kernel B: batched-speculative greedy (1 block, 256 threads) + epilogue.
// v2: 512-candidate rounds (2/thread) + parallel crossing-matrix precompute.
// ===========================================================================
__global__ void __launch_bounds__(TPB, 1) greedy_kernel(
    const int2* __restrict__ spans2, const int* __restrict__ spans,
    const float* __restrict__ scores, const int* __restrict__ order,
    const int* __restrict__ tnum_p, const int* __restrict__ keep_p,
    float* __restrict__ out, int N) {
  __shared__ unsigned tabP[MAXT + TPAD];  // hi16 = e2s(enc), lo16 = s2e+1
  __shared__ int2 tab[MAXT + TPAD];       // authoritative: .x=s2e, .y=e2s
  __shared__ unsigned long long acc[MAXK];
  __shared__ unsigned long long surv[BATCH];
  __shared__ unsigned long long Cmat[BATCH];   // in-group crossing rows
  __shared__ int wvs[8];                       // survivor counts per wave/half
  __shared__ int gcnt;

  const int tid = threadIdx.x;
  const int lane = tid & 63;
  const int wave = tid >> 6;
  const int T  = tnum_p[0];
  const int k0 = keep_p[0];
  const int k  = (k0 < MAXK) ? k0 : MAXK;

  for (int t = tid; t < MAXT + TPAD; t += TPB) {
    tab[t] = make_int2(-1, INT_MAX);
    tabP[t] = 0xFFFF0000u;               // s2e+1 = 0, e2s_enc = 0xFFFF
  }
  if (tid == 0) gcnt = 0;
  __syncthreads();

  // Each thread owns candidates j=tid (A) and j=256+tid (B) of every round.
  // ids prefetched 2 rounds ahead, spans 1 round ahead.
  int ccA = -1, csA = 0, ceA = 0, ccB = -1, csB = 0, ceB = 0;
  int nA = -1, nB = -1;
  if (tid < N)             ccA = order[tid];
  if (256 + tid < N)       ccB = order[256 + tid];
  if (BATCH + tid < N)     nA  = order[BATCH + tid];
  if (BATCH + 256 + tid < N) nB = order[BATCH + 256 + tid];
  if (ccA >= 0) { int2 sp = spans2[ccA]; csA = sp.x; ceA = sp.y; }
  if (ccB >= 0) { int2 sp = spans2[ccB]; csB = sp.x; ceB = sp.y; }

  int cnt = 0;
  for (int c0 = 0; c0 < N && cnt < k; c0 += BATCH) {
    // ---- prefetch next-round spans + next-next-round ids ----
    int pA = nA, psA = 0, peA = 0, pB = nB, psB = 0, peB = 0;
    if (pA >= 0) { int2 sp = spans2[pA]; psA = sp.x; peA = sp.y; }
    if (pB >= 0) { int2 sp = spans2[pB]; psB = sp.x; peB = sp.y; }
    int i2 = c0 + 2 * BATCH + tid;
    nA = (i2 < N) ? order[i2] : -1;
    nB = (i2 + 256 < N) ? order[i2 + 256] : -1;

    // ---- parallel pre-check vs packed tables (monotone -> speculative) ----
    bool ok0, ok1;
    {
      int w = ceA - csA;
      bool crossed = false;
      #pragma unroll
      for (int off = 0; off <= MAXW; ++off) {
        unsigned tv = tabP[csA + off];
        crossed |= ((off >= 1) & (off <= w) & ((tv & 0xFFFFu) > (unsigned)(ceA + 1)))
                 | ((off < w) & ((tv >> 16) < (unsigned)csA));
      }
      for (int off = MAXW + 1; off <= w; ++off) {   // generic fallback (unused)
        unsigned tv = tabP[csA + off];
        crossed |= ((tv & 0xFFFFu) > (unsigned)(ceA + 1));
        if (off < w) crossed |= ((tv >> 16) < (unsigned)csA);
      }
      ok0 = (ccA >= 0) && !crossed;
    }
    {
      int w = ceB - csB;
      bool crossed = false;
      #pragma unroll
      for (int off = 0; off <= MAXW; ++off) {
        unsigned tv = tabP[csB + off];
        crossed |= ((off >= 1) & (off <= w) & ((tv & 0xFFFFu) > (unsigned)(ceB + 1)))
                 | ((off < w) & ((tv >> 16) < (unsigned)csB));
      }
      for (int off = MAXW + 1; off <= w; ++off) {   // generic fallback (unused)
        unsigned tv = tabP[csB + off];
        crossed |= ((tv & 0xFFFFu) > (unsigned)(ceB + 1));
        if (off < w) crossed |= ((tv >> 16) < (unsigned)csB);
      }
      ok1 = (ccB >= 0) && !crossed;
    }

    // ---- order-preserving survivor compression -> LDS (512-wide) ----
    unsigned long long bal0 = __ballot(ok0);
    unsigned long long bal1 = __ballot(ok1);
    if (lane == 0) {
      wvs[wave]     = (int)__popcll(bal0);
      wvs[4 + wave] = (int)__popcll(bal1);
    }
    __syncthreads();
    int half0 = wvs[0] + wvs[1] + wvs[2] + wvs[3];
    int ns = half0 + wvs[4] + wvs[5] + wvs[6] + wvs[7];
    if (ok0) {
      int wb = 0;
      for (int w2 = 0; w2 < wave; ++w2) wb += wvs[w2];
      int pos = wb + (int)__popcll(bal0 & ((1ull << lane) - 1ull));
      surv[pos] = ((unsigned long long)(unsigned)csA << 48)
                | ((unsigned long long)(unsigned)ceA << 32)
                | (unsigned)ccA;
    }
    if (ok1) {
      int wb = half0;
      for (int w2 = 0; w2 < wave; ++w2) wb += wvs[4 + w2];
      int pos = wb + (int)__popcll(bal1 & ((1ull << lane) - 1ull));
      surv[pos] = ((unsigned long long)(unsigned)csB << 48)
                | ((unsigned long long)(unsigned)ceB << 32)
                | (unsigned)ccB;
    }
    __syncthreads();

    // ---- parallel in-group crossing-matrix precompute (table-independent) ----
    for (int v = tid; v < ns; v += TPB) {
      unsigned long long pk = surv[v];
      int gs = (int)(pk >> 48), ge = (int)((pk >> 32) & 0xFFFFu);
      int gbase = v & ~63;
      int m = ns - gbase; if (m > 64) m = 64;
      unsigned long long C = 0;
      for (int j = 0; j < m; ++j) {
        unsigned long long pj = surv[gbase + j];
        int sj = (int)(pj >> 48), ej = (int)((pj >> 32) & 0xFFFFu);
        bool cr = (gs < sj && sj <= ge && ej > ge) ||
                  (sj < gs && gs <= ej && ej < ge);
        C |= (unsigned long long)cr << j;
      }
      Cmat[v] = C;
    }
    __syncthreads();

    // ---- wave-0 resolution, 64 survivors at a time ----
    if (tid < 64) {
      bool dirty = false;      // any in-batch acceptance since pre-check?
      for (int g = 0; g < ns && cnt < k; g += 64) {
        int m = ns - g; if (m > 64) m = 64;
        bool act = lane < m;
        int gs = 0, ge = 0, gc = 0;
        unsigned long long C = 0;
        if (act) {
          unsigned long long pk = surv[g + lane];
          gs = (int)(pk >> 48);
          ge = (int)((pk >> 32) & 0xFFFFu);
          gc = (int)(unsigned)pk;
          C  = Cmat[g + lane];
        }
        bool pre = act;
        if (dirty) {           // re-check only when tables changed in-batch
          int gw = ge - gs;
          bool rc = false;
          #pragma unroll
          for (int off = 0; off <= MAXW; ++off) {
            unsigned tv = tabP[gs + off];
            rc |= ((off >= 1) & (off <= gw) & ((tv & 0xFFFFu) > (unsigned)(ge + 1)))
                | ((off < gw) & ((tv >> 16) < (unsigned)gs));
          }
          for (int off = MAXW + 1; off <= gw; ++off) {
            unsigned tv = tabP[gs + off];
            rc |= ((tv & 0xFFFFu) > (unsigned)(ge + 1));
            if (off < gw) rc |= ((tv >> 16) < (unsigned)gs);
          }
          pre = act && !rc;
        }
        unsigned long long preB = __ballot(pre);
        if (preB == 0ull) continue;
        int np = (int)__popcll(preB);
        unsigned long long lower = (1ull << lane) - 1ull;
        unsigned long long accm;
        int cnt0g = cnt;
        if (np == 1) {                       // single-survivor fast path
          accm = preB;
          cnt += 1;
        } else {
          if (cnt + np <= k) {
            // bulk: accept all with no earlier *surviving* in-group crosser
            bool easy = pre && ((C & lower & preB) == 0ull);
            accm = __ballot(easy);
            unsigned long long rem = preB & ~accm;
            while (rem) {
              unsigned long long kmask = __ballot((C & accm & lower) != 0ull);
              int j = __ffsll((long long)rem) - 1;
              rem &= rem - 1;
              if (!((kmask >> j) & 1ull)) accm |= 1ull << j;
            }
            cnt += (int)__popcll(accm);
          } else {
            // k-cap mode: strict serial order incl. count limit
            accm = 0ull;
            unsigned long long rem = preB;
            while (rem && cnt < k) {
              unsigned long long kmask = __ballot((C & accm & lower) != 0ull);
              int j = __ffsll((long long)rem) - 1;
              rem &= rem - 1;
              if (!((kmask >> j) & 1ull)) { accm |= 1ull << j; cnt++; }
            }
          }
        }
        bool accme = ((accm >> lane) & 1ull) != 0ull;
        if (accme) {
          int rank = (int)__popcll(accm & lower);
          acc[cnt0g + rank] =
              ((unsigned long long)(unsigned)(gs * T + ge) << 32) | (unsigned)gc;
          atomicMax(&tab[gs].x, ge);
          atomicMin(&tab[ge].y, gs);
        }
        if (accme) {        // same-wave DS in-order: reads see all atomics
          int2 tv = tab[gs];
          tabP[gs] = ((unsigned)(tv.y > 65535 ? 65535 : tv.y) << 16)
                   | (unsigned)(tv.x + 1);
          int2 tv2 = tab[ge];
          tabP[ge] = ((unsigned)(tv2.y > 65535 ? 65535 : tv2.y) << 16)
                   | (unsigned)(tv2.x + 1);
        }
        if (accm) dirty = true;
      }
      if (lane == 0) gcnt = cnt;
    }
    __syncthreads();
    cnt = gcnt;
    ccA = pA; csA = psA; ceA = peA;
    ccB = pB; csB = psB; ceB = peB;
  }

  // ---- bitonic ascending sort of acc[0..cnt) by (s*T+e, cand) ----
  int M = 2;
  while (M < cnt) M <<= 1;
  for (int j = tid; j < M; j += TPB)
    if (j >= cnt) acc[j] = ~0ull;
  __syncthreads();
  for (int kk = 2; kk <= M; kk <<= 1) {
    for (int jj = kk >> 1; jj > 0; jj >>= 1) {
      for (int i3 = tid; i3 < M; i3 += TPB) {
        int ixj = i3 ^ jj;
        if (ixj > i3) {
          unsigned long long a = acc[i3], b = acc[ixj];
          bool up = ((i3 & kk) == 0);
          if ((a > b) == up) { acc[i3] = b; acc[ixj] = a; }
        }
      }
      __syncthreads();
    }
  }

  // ---- epilogue: scores | idx | spans | valid, all f32 ----
  for (int j = tid; j < k0; j += TPB) {
    if (j < cnt) {
      int cand = (int)(acc[j] & 0xFFFFFFFFu);
      out[j]                  = scores[cand];
      out[k0 + j]             = (float)cand;
      out[2 * k0 + 2 * j]     = (float)spans[2 * cand];
      out[2 * k0 + 2 * j + 1] = (float)spans[2 * cand + 1];
      out[4 * k0 + j]         = 1.0f;
    } else {
      out[j]                  = 0.0f;
      out[k0 + j]             = 0.0f;
      out[2 * k0 + 2 * j]     = 0.0f;
      out[2 * k0 + 2 * j + 1] = 0.0f;
      out[4 * k0 + j]         = 0.0f;
    }
  }
}

extern "C" void kernel_launch(void* const* d_in, const int* in_sizes, int n_in,
                              void* d_out, int out_size, void* d_ws, size_t ws_size,
                              hipStream_t stream) {
  const int*   spans  = (const int*)d_in[0];
  const float* scores = (const float*)d_in[1];
  const float* mask   = (const float*)d_in[2];
  const int*   tnum   = (const int*)d_in[3];
  const int*   keep   = (const int*)d_in[4];
  const int N = in_sizes[1];
  const int nT = (N + TILE - 1) / TILE;   // 60 for N=61440

  // ws: ctr[32] | ghist[4*256] | tileCnt[nT*256] | keysA | keysB | idxA | idxB
  unsigned* ctr     = (unsigned*)d_ws;
  unsigned* ghist   = ctr + 32;
  unsigned* tileCnt = ghist + 4 * 256;
  unsigned* keysA   = tileCnt + (size_t)nT * 256;
  unsigned* keysB   = keysA + N;
  int*      idxA    = (int*)(keysB + N);
  int*      idxB    = idxA + N;
  float*    out     = (float*)d_out;

  hipMemsetAsync(ctr, 0, (32 + 4 * 256) * sizeof(unsigned), stream);

  sort_kernel<<<nT, TPB, 0, stream>>>(scores, mask, N, nT, ctr, ghist,
                                      tileCnt, keysA, keysB, idxA, idxB);
  greedy_kernel<<<1, TPB, 0, stream>>>((const int2*)spans, spans, scores,
                                       idxA, tnum, keep, out, N);
}